// Round 5
// baseline (513.158 us; speedup 1.0000x reference)
//
#include <hip/hip_runtime.h>

#define TSTEPS 12
#define NNODES 50000
#define DIN 32
#define HDIM 128
#define DECS 7

// Mixed-tile grid: 53 blocks x 80 rows + 715 blocks x 64 rows = 50000 rows exactly.
// 768 = 3*256 -> exactly 3 dispatch rounds at 1 block/CU. Lower bound is
// ceil(3125 16-row units / 256 CU) = 13 units/CU = 3.25*T64 -- achieved exactly.
#define N80 53
#define NB 768
#define RTMAX 5
#define ROWSMAX 80

#define HS 136   // halves per row for e/h buffers (272B stride; b128-aligned)
#define XS 36    // halves per row per timestep for x tile
#define ESZ (ROWSMAX * HS)   // 10880 halves per e/h buffer

typedef _Float16 half_t;
typedef _Float16 half8 __attribute__((ext_vector_type(8)));
typedef float float4_ __attribute__((ext_vector_type(4)));

// ---------------- shared memory layout (byte offsets) ------------------
// [0]      xa   : 12*80*36 halves = 69120 B          (encoder only)
// [69120]  e0/e1: 2 * 21760 B                        (encoder only)
// [112640] h0/h1: 2 * 21760 B
// [156160] pred : 2*4*80 floats = 2560 B  (double-buffered for merged decoder)
// decoder alias: zx (per-lane packed z_x) at [0, 81920) over dead xa+e0
#define SM_BYTES 158720
#define E_OFF 69120
#define H_OFF 112640
#define PRED_OFF 156160
#define ZX_PLANE_H 20480   // halves: 8 waves * 5 rt * 64 lanes * 8

#define SCL_S 1.4426950409f   // log2(e)   for gates i,f,o
#define SCL_G 2.8853900818f   // 2*log2(e) for gate g

#if __has_builtin(__builtin_amdgcn_exp2f)
#define EXP2F __builtin_amdgcn_exp2f
#else
#define EXP2F exp2f
#endif
#if __has_builtin(__builtin_amdgcn_rcpf)
#define RCPF __builtin_amdgcn_rcpf
#else
#define RCPF(x) (1.0f / (x))
#endif

// z pre-scaled by log2(e) (gates i,f,o) and 2*log2(e) (gate g) via weight/bias
// folding at load time. Cell state kept PRE-SCALED: cp = 2*log2(e)*c, so the
// output tanh needs no multiply (ac = 2^-cp). sigma(f)'s rcp folded into the
// i*g rcp via the common denominator D1*D2 = (1+af)(1+ai)(1+ag).
// 7 transcendentals/element (5 exp2 + 2 rcp).
__device__ __forceinline__ float lstm_one(float zi, float zf, float zg, float zo, float& cp) {
    float ai = EXP2F(-zi);
    float af = EXP2F(-zf);
    float ag = EXP2F(-zg);
    float ao = EXP2F(-zo);
    float D1 = 1.0f + af;
    float tg = 1.0f + ag;
    float D2 = fmaf(ai, tg, tg);                          // (1+ai)(1+ag)
    float M  = fmaf(ag, -SCL_G, SCL_G);                   // 2.885*(1-ag)
    float num = fmaf(M, D1, cp * D2);
    cp = num * RCPF(D1 * D2);
    float ac = EXP2F(-cp);                                // e^(-2c)
    float tc = 1.0f + ac;
    return (1.0f - ac) * RCPF(fmaf(ao, tc, tc));          // sigma(o)*tanh(c)
}

// Direct fragment load from the ORIGINAL fp32 weight array (no prep kernel):
// a B-fragment is 8 CONSECUTIVE columns of one row -> two contiguous float4
// loads + prescale + fp16 pack. One-time cost per block-phase (~900 cyc/wave).
__device__ __forceinline__ half8 load_frag(const float* __restrict__ W,
                                           int row, int col, float scl) {
    const float* p = W + (size_t)row * 128 + col;
    float4_ a0 = *(const float4_*)p;
    float4_ a1 = *(const float4_*)(p + 4);
    half8 h;
    h[0] = (half_t)(a0[0] * scl); h[1] = (half_t)(a0[1] * scl);
    h[2] = (half_t)(a0[2] * scl); h[3] = (half_t)(a0[3] * scl);
    h[4] = (half_t)(a1[0] * scl); h[5] = (half_t)(a1[1] * scl);
    h[6] = (half_t)(a1[2] * scl); h[7] = (half_t)(a1[3] * scl);
    return h;
}
__device__ __forceinline__ half8 load_frag32(const float* __restrict__ W,
                                             int row, int col) {
    const float* p = W + (size_t)row * 32 + col;
    float4_ a0 = *(const float4_*)p;
    float4_ a1 = *(const float4_*)(p + 4);
    half8 h;
    h[0] = (half_t)a0[0]; h[1] = (half_t)a0[1]; h[2] = (half_t)a0[2]; h[3] = (half_t)a0[3];
    h[4] = (half_t)a1[0]; h[5] = (half_t)a1[1]; h[6] = (half_t)a1[2]; h[7] = (half_t)a1[3];
    return h;
}

// LSTM step for RT row-tiles (RT in {4,5}, wave-uniform). 8 waves, H split 8-way.
// rt outermost: activation VALU of rt overlaps the independent MFMA chain of rt+1.
// Callers may swap (eA,wfA) <-> (hA,wfB): z = e*Wi + h*Wh commutes.
__device__ __forceinline__ void lstm_step(
    const half_t* __restrict__ eA, const half_t* __restrict__ hA, half_t* __restrict__ hOut,
    const half8 (&wfA)[4][4], const half8 (&wfB)[4][4],
    const float bR[4], float (&cS)[RTMAX][4],
    int w, int q, int l15, int RT) {
#pragma unroll
    for (int rt = 0; rt < RTMAX; ++rt) {
        if (rt < RT) {
            float4_ acc[4];
#pragma unroll
            for (int g = 0; g < 4; ++g) {
                float b = bR[g];
                acc[g][0] = b; acc[g][1] = b; acc[g][2] = b; acc[g][3] = b;
            }
            __builtin_amdgcn_s_setprio(1);
#pragma unroll
            for (int kb = 0; kb < 4; ++kb) {
                half8 ae = *(const half8*)(eA + (rt * 16 + l15) * HS + kb * 32 + q * 8);
                half8 ah = *(const half8*)(hA + (rt * 16 + l15) * HS + kb * 32 + q * 8);
#pragma unroll
                for (int g = 0; g < 4; ++g) {
                    acc[g] = __builtin_amdgcn_mfma_f32_16x16x32_f16(ae, wfA[g][kb], acc[g], 0, 0, 0);
                    acc[g] = __builtin_amdgcn_mfma_f32_16x16x32_f16(ah, wfB[g][kb], acc[g], 0, 0, 0);
                }
            }
            __builtin_amdgcn_s_setprio(0);
            // C-layout: row = rt*16 + q*4 + r, col (within H) = w*16 + l15
#pragma unroll
            for (int r = 0; r < 4; ++r) {
                float h = lstm_one(acc[0][r], acc[1][r], acc[2][r], acc[3][r], cS[rt][r]);
                hOut[(rt * 16 + q * 4 + r) * HS + w * 16 + l15] = (half_t)h;
            }
        }
    }
}

// Decoder LSTM step: input-GEMM replaced by per-lane zx read (d_in fixed across steps).
__device__ __forceinline__ void lstm_step_dec(
    const half_t* __restrict__ zx, const half_t* __restrict__ hA, half_t* __restrict__ hOut,
    const half8 (&wfh)[4][4], float (&cS)[RTMAX][4],
    int w, int q, int l15, int lane, int RT) {
#pragma unroll
    for (int rt = 0; rt < RTMAX; ++rt) {
        if (rt < RT) {
            const half_t* p0 = zx + ((w * RTMAX + rt) * 64 + lane) * 8;
            half8 z0 = *(const half8*)p0;                 // gates i,f
            half8 z1 = *(const half8*)(p0 + ZX_PLANE_H);  // gates g,o
            float4_ acc[4];
#pragma unroll
            for (int r = 0; r < 4; ++r) {
                acc[0][r] = (float)z0[r];
                acc[1][r] = (float)z0[4 + r];
                acc[2][r] = (float)z1[r];
                acc[3][r] = (float)z1[4 + r];
            }
            __builtin_amdgcn_s_setprio(1);
#pragma unroll
            for (int kb = 0; kb < 4; ++kb) {
                half8 ah = *(const half8*)(hA + (rt * 16 + l15) * HS + kb * 32 + q * 8);
#pragma unroll
                for (int g = 0; g < 4; ++g)
                    acc[g] = __builtin_amdgcn_mfma_f32_16x16x32_f16(ah, wfh[g][kb], acc[g], 0, 0, 0);
            }
            __builtin_amdgcn_s_setprio(0);
#pragma unroll
            for (int r = 0; r < 4; ++r) {
                float h = lstm_one(acc[0][r], acc[1][r], acc[2][r], acc[3][r], cS[rt][r]);
                hOut[(rt * 16 + q * 4 + r) * HS + w * 16 + l15] = (half_t)h;
            }
        }
    }
}

// e_t = relu(x_t @ encW^T + enc_b); wave w computes e cols [16w, 16w+16)
__device__ __forceinline__ void enc_proj(
    const half_t* __restrict__ xa, half_t* __restrict__ eOut,
    half8 encWf, float benc, int t, int w, int q, int l15, int RT) {
#pragma unroll
    for (int rt = 0; rt < RTMAX; ++rt) {
        if (rt < RT) {
            half8 af = *(const half8*)(xa + ((t * ROWSMAX) + rt * 16 + l15) * XS + q * 8);
            float4_ a;
            a[0] = benc; a[1] = benc; a[2] = benc; a[3] = benc;
            a = __builtin_amdgcn_mfma_f32_16x16x32_f16(af, encWf, a, 0, 0, 0);
#pragma unroll
            for (int r = 0; r < 4; ++r) {
                float v = a[r];
                v = v > 0.f ? v : 0.f;
                eOut[(rt * 16 + q * 4 + r) * HS + w * 16 + l15] = (half_t)v;
            }
        }
    }
}

// head: o = relu(h @ fc1^T + b1); per-(ct,row) partial dot with fc2 into pred[ct][row].
// wave w: fc1 col-tile (w&3); row-tiles rt = gg, gg+2, gg+4 (gg = w>>2)
__device__ __forceinline__ void head_step(
    const half_t* __restrict__ hc, float (*pred)[ROWSMAX],
    const half8 (&fc1f)[4], float bf1, float wf2,
    int w, int q, int l15, int gg, int RT) {
#pragma unroll
    for (int rp = 0; rp < 3; ++rp) {
        int rt = gg + rp * 2;
        if (rt < RT) {
            float4_ hacc;
            hacc[0] = bf1; hacc[1] = bf1; hacc[2] = bf1; hacc[3] = bf1;
#pragma unroll
            for (int kb = 0; kb < 4; ++kb) {
                half8 af = *(const half8*)(hc + (rt * 16 + l15) * HS + kb * 32 + q * 8);
                hacc = __builtin_amdgcn_mfma_f32_16x16x32_f16(af, fc1f[kb], hacc, 0, 0, 0);
            }
#pragma unroll
            for (int r = 0; r < 4; ++r) {
                float v = hacc[r];
                v = v > 0.f ? v : 0.f;
                v *= wf2;
                v += __shfl_xor(v, 1, 64);
                v += __shfl_xor(v, 2, 64);
                v += __shfl_xor(v, 4, 64);
                v += __shfl_xor(v, 8, 64);
                if (l15 == 0) pred[w & 3][rt * 16 + q * 4 + r] = v;
            }
        }
    }
}

__global__ __launch_bounds__(512, 2) void seq2seq_main_k(
    const float* __restrict__ x,
    const float* __restrict__ enc_W, const float* __restrict__ enc_b,
    const float* __restrict__ Wih_e, const float* __restrict__ Whh_e,
    const float* __restrict__ bih_e, const float* __restrict__ bhh_e,
    const float* __restrict__ Wih_d, const float* __restrict__ Whh_d,
    const float* __restrict__ bih_d, const float* __restrict__ bhh_d,
    const float* __restrict__ fc1_W, const float* __restrict__ fc1_b,
    const float* __restrict__ fc2_W, const float* __restrict__ fc2_b,
    float* __restrict__ out) {
    __shared__ __align__(16) char smem[SM_BYTES];
    half_t* xa = (half_t*)smem;
    half_t* eB = (half_t*)(smem + E_OFF);
    half_t* hB = (half_t*)(smem + H_OFF);
    float (*pred)[4][ROWSMAX] = (float(*)[4][ROWSMAX])(smem + PRED_OFF);  // [2][4][80]
    half_t* zx = (half_t*)smem;   // decoder alias over dead xa+e0

    const int tid  = threadIdx.x;
    const int lane = tid & 63;
    const int w    = tid >> 6;        // wave 0..7
    const int q    = lane >> 4;
    const int l15  = lane & 15;
    // SIMD-phase stagger: waves w and w+4 share a SIMD (round-robin mapping);
    // opposite step-phase packs one wave's MFMA burst against the other's
    // activation/LDS burst.
    const int ph   = (w >> 2) & 1;
    const int bid  = blockIdx.x;
    const int big  = (bid < N80);
    const int RT   = big ? 5 : 4;
    const int rows = RT << 4;
    const int n0   = big ? bid * 80 : (N80 * 80 + (bid - N80) * 64);

    // per-wave biases (prescaled at load): z col = g*128 + w*16 + l15
    float beR[4], bdR[4];
#pragma unroll
    for (int g = 0; g < 4; ++g) {
        const float scl = (g == 2) ? SCL_G : SCL_S;
        int col = g * 128 + w * 16 + l15;
        beR[g] = (bih_e[col] + bhh_e[col]) * scl;
        bdR[g] = (bih_d[col] + bhh_d[col]) * scl;
    }
    float benc = enc_b[w * 16 + l15];

    // stage ALL x timesteps into LDS (fp16). 12 t * 80 rows * 4 chunks = 3840 units max.
    for (int it = 0; it < 8; ++it) {
        int unit = tid + it * 512;
        if (unit >= TSTEPS * ROWSMAX * 4) break;
        int t    = unit / (ROWSMAX * 4);
        int rest = unit - t * (ROWSMAX * 4);
        int row  = rest >> 2;
        int c0   = (rest & 3) * 8;
        if (row < rows) {
            const float* p = x + ((size_t)t * NNODES + (n0 + row)) * DIN + c0;
            float4_ a0 = *(const float4_*)p;
            float4_ a1 = *(const float4_*)(p + 4);
            half8 hv;
            hv[0] = (half_t)a0[0]; hv[1] = (half_t)a0[1]; hv[2] = (half_t)a0[2]; hv[3] = (half_t)a0[3];
            hv[4] = (half_t)a1[0]; hv[5] = (half_t)a1[1]; hv[6] = (half_t)a1[2]; hv[7] = (half_t)a1[3];
            *(half8*)(xa + (t * ROWSMAX + row) * XS + c0) = hv;
        }
    }

    // zero initial h (buffer 0)
    for (int i = tid; i < rows * HS; i += 512) hB[i] = (half_t)0.0f;

    float c_reg[RTMAX][4];
#pragma unroll
    for (int rt = 0; rt < RTMAX; ++rt)
#pragma unroll
        for (int r = 0; r < 4; ++r) c_reg[rt][r] = 0.0f;

    // ---- encoder weights: direct from fp32 arrays (prescaled, packed to fp16).
    // sched_barrier per gate-group caps transient float4 register pressure.
    half8 wfi[4][4], wfh[4][4];
#pragma unroll
    for (int g = 0; g < 4; ++g) {
        const float scl = (g == 2) ? SCL_G : SCL_S;
        int row = g * 128 + w * 16 + l15;
#pragma unroll
        for (int kb = 0; kb < 4; ++kb) {
            wfi[g][kb] = load_frag(Wih_e, row, kb * 32 + q * 8, scl);
            wfh[g][kb] = load_frag(Whh_e, row, kb * 32 + q * 8, scl);
        }
        __builtin_amdgcn_sched_barrier(0);
    }
    half8 encWf = load_frag32(enc_W, w * 16 + l15, q * 8);

    __syncthreads();  // xa + h0 ready

    enc_proj(xa, eB, encWf, benc, 0, w, q, l15, RT);
    __syncthreads();  // e0 ready

    int cur = 0;
    // ================= encoder: one barrier per step, phase-staggered =================
    for (int t = 0; t < TSTEPS; ++t) {
        const half_t* eCur  = eB + (t & 1) * ESZ;
        half_t*       eNext = eB + ((t & 1) ^ 1) * ESZ;
        const half_t* hCur  = hB + cur * ESZ;
        half_t*       hNext = hB + (cur ^ 1) * ESZ;
        if (!ph) {
            lstm_step(eCur, hCur, hNext, wfi, wfh, beR, c_reg, w, q, l15, RT);
            if (t + 1 < TSTEPS)
                enc_proj(xa, eNext, encWf, benc, t + 1, w, q, l15, RT);
        } else {
            if (t + 1 < TSTEPS)
                enc_proj(xa, eNext, encWf, benc, t + 1, w, q, l15, RT);
            lstm_step(hCur, eCur, hNext, wfh, wfi, beR, c_reg, w, q, l15, RT);
        }
        __syncthreads();
        cur ^= 1;
    }
    // cur == 0; hB[cur] = final encoder h == d_in. xa and e are dead.

    // ---- decoder weights into the same registers (direct fp32 load); head params ----
#pragma unroll
    for (int g = 0; g < 4; ++g) {
        const float scl = (g == 2) ? SCL_G : SCL_S;
        int row = g * 128 + w * 16 + l15;
#pragma unroll
        for (int kb = 0; kb < 4; ++kb) {
            wfi[g][kb] = load_frag(Wih_d, row, kb * 32 + q * 8, scl);
            wfh[g][kb] = load_frag(Whh_d, row, kb * 32 + q * 8, scl);
        }
        __builtin_amdgcn_sched_barrier(0);
    }
    half8 fc1f[4];
#pragma unroll
    for (int kb = 0; kb < 4; ++kb)
        fc1f[kb] = load_frag(fc1_W, (w & 3) * 16 + l15, kb * 32 + q * 8, 1.0f);
    float bf1 = fc1_b[(w & 3) * 16 + l15];
    float wf2 = fc2_W[(w & 3) * 16 + l15];
    float bf2 = fc2_b[0];
    const int gg = w >> 2;

    // ---- z_x = d_in @ WihD^T + b_d, once (d_in fixed across decoder steps).
    // Per-lane-private packed fp16 layout -> no barrier needed; aliases dead xa/e0.
    {
        const half_t* hfin = hB + cur * ESZ;
#pragma unroll
        for (int rt = 0; rt < RTMAX; ++rt) {
            if (rt < RT) {
                float4_ acc[4];
#pragma unroll
                for (int g = 0; g < 4; ++g) {
                    float b = bdR[g];
                    acc[g][0] = b; acc[g][1] = b; acc[g][2] = b; acc[g][3] = b;
                }
#pragma unroll
                for (int kb = 0; kb < 4; ++kb) {
                    half8 ah = *(const half8*)(hfin + (rt * 16 + l15) * HS + kb * 32 + q * 8);
#pragma unroll
                    for (int g = 0; g < 4; ++g)
                        acc[g] = __builtin_amdgcn_mfma_f32_16x16x32_f16(ah, wfi[g][kb], acc[g], 0, 0, 0);
                }
                half8 z0, z1;
#pragma unroll
                for (int r = 0; r < 4; ++r) {
                    z0[r]     = (half_t)acc[0][r];
                    z0[4 + r] = (half_t)acc[1][r];
                    z1[r]     = (half_t)acc[2][r];
                    z1[4 + r] = (half_t)acc[3][r];
                }
                half_t* p0 = zx + ((w * RTMAX + rt) * 64 + lane) * 8;
                *(half8*)p0 = z0;
                *(half8*)(p0 + ZX_PLANE_H) = z1;
            }
        }
    }

    // ================= decoder: merged segments =================
    // Segment s: { lstm_dec(s) ∥ head(s-1) ∥ out(s-2) } ; barrier.
    // head/lstm only READ h[hc]; pred double-buffer separates head(s-1)/out(s-2).
    int hc = cur;
    for (int s = 0; s < DECS; ++s) {
        lstm_step_dec(zx, hB + hc * ESZ, hB + (hc ^ 1) * ESZ, wfh, c_reg, w, q, l15, lane, RT);
        if (s >= 1)
            head_step(hB + hc * ESZ, pred[(s - 1) & 1], fc1f, bf1, wf2, w, q, l15, gg, RT);
        if (s >= 2 && tid < rows) {
            float sum = pred[s & 1][0][tid] + pred[s & 1][1][tid]
                      + pred[s & 1][2][tid] + pred[s & 1][3][tid] + bf2;
            out[(size_t)(n0 + tid) * DECS + (s - 2)] = sum;
        }
        __syncthreads();
        hc ^= 1;
    }
    // tail: h[hc] = output of lstm(6)
    head_step(hB + hc * ESZ, pred[0], fc1f, bf1, wf2, w, q, l15, gg, RT);  // head(6)
    if (tid < rows) {  // out(5) from pred[1]
        float sum = pred[1][0][tid] + pred[1][1][tid] + pred[1][2][tid] + pred[1][3][tid] + bf2;
        out[(size_t)(n0 + tid) * DECS + 5] = sum;
    }
    __syncthreads();
    if (tid < rows) {  // out(6) from pred[0]
        float sum = pred[0][0][tid] + pred[0][1][tid] + pred[0][2][tid] + pred[0][3][tid] + bf2;
        out[(size_t)(n0 + tid) * DECS + 6] = sum;
    }
}

extern "C" void kernel_launch(void* const* d_in, const int* in_sizes, int n_in,
                              void* d_out, int out_size, void* d_ws, size_t ws_size,
                              hipStream_t stream) {
    (void)in_sizes; (void)n_in; (void)out_size; (void)d_ws; (void)ws_size;
    const float* x     = (const float*)d_in[0];
    const float* enc_W = (const float*)d_in[1];
    const float* enc_b = (const float*)d_in[2];
    const float* Wih_e = (const float*)d_in[3];
    const float* Whh_e = (const float*)d_in[4];
    const float* bih_e = (const float*)d_in[5];
    const float* bhh_e = (const float*)d_in[6];
    const float* Wih_d = (const float*)d_in[7];
    const float* Whh_d = (const float*)d_in[8];
    const float* bih_d = (const float*)d_in[9];
    const float* bhh_d = (const float*)d_in[10];
    const float* fc1_W = (const float*)d_in[11];
    const float* fc1_b = (const float*)d_in[12];
    const float* fc2_W = (const float*)d_in[13];
    const float* fc2_b = (const float*)d_in[14];

    // single launch: weights packed/prescaled in-kernel (no prep dispatch, no workspace)
    seq2seq_main_k<<<NB, 512, 0, stream>>>(x, enc_W, enc_b, Wih_e, Whh_e, bih_e, bhh_e,
                                           Wih_d, Whh_d, bih_d, bhh_d,
                                           fc1_W, fc1_b, fc2_W, fc2_b, (float*)d_out);
}

// Round 6
// 386.398 us; speedup vs baseline: 1.3281x; 1.3281x over previous
//
#include <hip/hip_runtime.h>

#define TSTEPS 12
#define NNODES 50000
#define DIN 32
#define HDIM 128
#define DECS 7

// Mixed-tile grid: 53 blocks x 80 rows + 715 blocks x 64 rows = 50000 rows exactly.
// 768 = 3*256 -> exactly 3 dispatch rounds at 1 block/CU. Lower bound is
// ceil(3125 16-row units / 256 CU) = 13 units/CU = 3.25*T64 -- achieved exactly.
#define N80 53
#define NB 768
#define RTMAX 5
#define ROWSMAX 80

#define HS 136   // halves per row for e/h buffers (272B stride; b128-aligned, reads bank-balanced)
#define XS 36    // halves per row per timestep for x tile
#define ESZ (ROWSMAX * HS)   // 10880 halves per e/h buffer

typedef _Float16 half_t;
typedef _Float16 half8 __attribute__((ext_vector_type(8)));
typedef float float4_ __attribute__((ext_vector_type(4)));

// ---------------- workspace layout (halves then floats) ----------------
// halves: [0] WihE 65536 | [65536] WhhE | [131072] WihD | [196608] WhhD |
//         [262144] encW 4096 | [266240] fc1 8192   (total 274432 halves)
// floats at byte 548864: b_e[512], b_d[512]
// NOTE (R5 post-mortem): in-kernel fp32->fp16 weight conversion spills
// (WRITE_SIZE 1.4->148 MB); the prep kernel + workspace is the right structure.
#define WS_FLOAT_OFF 548864

// ---------------- shared memory layout (byte offsets) ------------------
// [0]      xa   : 12*80*36 halves = 69120 B          (encoder only)
// [69120]  e0/e1: 2 * 21760 B                        (encoder only)
// [112640] h0/h1: 2 * 21760 B
// [156160] pred : 2*4*80 floats = 2560 B  (double-buffered for merged decoder)
// decoder alias: zx (per-lane packed z_x) at [0, 81920) over dead xa+e0
#define SM_BYTES 158720
#define E_OFF 69120
#define H_OFF 112640
#define PRED_OFF 156160
#define ZX_PLANE_H 20480   // halves: 8 waves * 5 rt * 64 lanes * 8

#define SCL_S 1.4426950409f   // log2(e)   for gates i,f,o
#define SCL_G 2.8853900818f   // 2*log2(e) for gate g

#if __has_builtin(__builtin_amdgcn_exp2f)
#define EXP2F __builtin_amdgcn_exp2f
#else
#define EXP2F exp2f
#endif
#if __has_builtin(__builtin_amdgcn_rcpf)
#define RCPF __builtin_amdgcn_rcpf
#else
#define RCPF(x) (1.0f / (x))
#endif

// z pre-scaled by log2(e) (gates i,f,o) and 2*log2(e) (gate g) via weight/bias
// folding in prep. Cell state kept PRE-SCALED: cp = 2*log2(e)*c, so the output
// tanh needs no multiply (ac = 2^-cp). sigma(f)'s rcp folded into the i*g rcp
// via the common denominator D1*D2 = (1+af)(1+ai)(1+ag).
// 7 transcendentals/element (5 exp2 + 2 rcp).
__device__ __forceinline__ float lstm_one(float zi, float zf, float zg, float zo, float& cp) {
    float ai = EXP2F(-zi);
    float af = EXP2F(-zf);
    float ag = EXP2F(-zg);
    float ao = EXP2F(-zo);
    float D1 = 1.0f + af;
    float tg = 1.0f + ag;
    float D2 = fmaf(ai, tg, tg);                          // (1+ai)(1+ag)
    float M  = fmaf(ag, -SCL_G, SCL_G);                   // 2.885*(1-ag)
    float num = fmaf(M, D1, cp * D2);
    cp = num * RCPF(D1 * D2);
    float ac = EXP2F(-cp);                                // e^(-2c)
    float tc = 1.0f + ac;
    return (1.0f - ac) * RCPF(fmaf(ao, tc, tc));          // sigma(o)*tanh(c)
}

// Fused prep: pack all 6 weight matrices into fragment-major fp16 + bias sums.
// LSTM weights/biases prescaled by log2(e) (i,f,o rows) or 2*log2(e) (g rows).
// Pack formula: dst[((ct*KB+kb)*64 + lane)*8 + j] = src[ct*16+(lane&15)][kb*32+(lane>>4)*8+j]
__global__ void prep_all_k(const float* __restrict__ Wih_e, const float* __restrict__ Whh_e,
                           const float* __restrict__ Wih_d, const float* __restrict__ Whh_d,
                           const float* __restrict__ enc_W, const float* __restrict__ fc1_W,
                           const float* __restrict__ bih_e, const float* __restrict__ bhh_e,
                           const float* __restrict__ bih_d, const float* __restrict__ bhh_d,
                           half_t* __restrict__ wsh, float* __restrict__ be, float* __restrict__ bd) {
    int tid = blockIdx.x * blockDim.x + threadIdx.x;
    if (tid < 262144) {
        int r = tid >> 16;
        int t = tid & 65535;
        const float* src = (r == 0) ? Wih_e : (r == 1) ? Whh_e : (r == 2) ? Wih_d : Whh_d;
        int j    = t & 7;
        int lane = (t >> 3) & 63;
        int rest = t >> 9;
        int kb   = rest & 3;
        int ct   = rest >> 2;
        int row  = ct * 16 + (lane & 15);
        int col  = kb * 32 + ((lane >> 4) << 3) + j;
        float scl = ((ct >> 3) == 2) ? SCL_G : SCL_S;  // gate g : i,f,o
        wsh[tid] = (half_t)(src[row * 128 + col] * scl);
    } else if (tid < 266240) {
        int t    = tid - 262144;
        int j    = t & 7;
        int lane = (t >> 3) & 63;
        int ct   = t >> 9;
        int row  = ct * 16 + (lane & 15);
        int col  = ((lane >> 4) << 3) + j;
        wsh[tid] = (half_t)enc_W[row * 32 + col];
    } else if (tid < 274432) {
        int t    = tid - 266240;
        int j    = t & 7;
        int lane = (t >> 3) & 63;
        int rest = t >> 9;
        int kb   = rest & 3;
        int ct   = rest >> 2;
        int row  = ct * 16 + (lane & 15);
        int col  = kb * 32 + ((lane >> 4) << 3) + j;
        wsh[tid] = (half_t)fc1_W[row * 128 + col];
    } else if (tid < 274944) {
        int t = tid - 274432;
        float scl = ((t >> 7) == 2) ? SCL_G : SCL_S;
        be[t] = (bih_e[t] + bhh_e[t]) * scl;
        bd[t] = (bih_d[t] + bhh_d[t]) * scl;
    }
}

// LSTM step for RT row-tiles (RT in {4,5}, wave-uniform). 8 waves, H split 8-way.
// rt outermost: activation VALU of rt overlaps the independent MFMA chain of rt+1.
// Callers may swap (eA,wfA) <-> (hA,wfB): z = e*Wi + h*Wh commutes.
__device__ __forceinline__ void lstm_step(
    const half_t* __restrict__ eA, const half_t* __restrict__ hA, half_t* __restrict__ hOut,
    const half8 (&wfA)[4][4], const half8 (&wfB)[4][4],
    const float bR[4], float (&cS)[RTMAX][4],
    int w, int q, int l15, int RT) {
#pragma unroll
    for (int rt = 0; rt < RTMAX; ++rt) {
        if (rt < RT) {
            float4_ acc[4];
#pragma unroll
            for (int g = 0; g < 4; ++g) {
                float b = bR[g];
                acc[g][0] = b; acc[g][1] = b; acc[g][2] = b; acc[g][3] = b;
            }
            __builtin_amdgcn_s_setprio(1);
#pragma unroll
            for (int kb = 0; kb < 4; ++kb) {
                half8 ae = *(const half8*)(eA + (rt * 16 + l15) * HS + kb * 32 + q * 8);
                half8 ah = *(const half8*)(hA + (rt * 16 + l15) * HS + kb * 32 + q * 8);
#pragma unroll
                for (int g = 0; g < 4; ++g) {
                    acc[g] = __builtin_amdgcn_mfma_f32_16x16x32_f16(ae, wfA[g][kb], acc[g], 0, 0, 0);
                    acc[g] = __builtin_amdgcn_mfma_f32_16x16x32_f16(ah, wfB[g][kb], acc[g], 0, 0, 0);
                }
            }
            __builtin_amdgcn_s_setprio(0);
            // C-layout: row = rt*16 + q*4 + r, col (within H) = w*16 + l15
#pragma unroll
            for (int r = 0; r < 4; ++r) {
                float h = lstm_one(acc[0][r], acc[1][r], acc[2][r], acc[3][r], cS[rt][r]);
                hOut[(rt * 16 + q * 4 + r) * HS + w * 16 + l15] = (half_t)h;
            }
        }
    }
}

// First encoder step: h == 0, so only the input-GEMM contributes (skips 64 MFMA +
// 16 LDS reads per wave, and lets the block skip the h-zero-fill entirely).
// cS enters as 0 -> lstm_one's f*c path is exactly 0, numerically identical.
__device__ __forceinline__ void lstm_step0(
    const half_t* __restrict__ eA, half_t* __restrict__ hOut,
    const half8 (&wfA)[4][4],
    const float bR[4], float (&cS)[RTMAX][4],
    int w, int q, int l15, int RT) {
#pragma unroll
    for (int rt = 0; rt < RTMAX; ++rt) {
        if (rt < RT) {
            float4_ acc[4];
#pragma unroll
            for (int g = 0; g < 4; ++g) {
                float b = bR[g];
                acc[g][0] = b; acc[g][1] = b; acc[g][2] = b; acc[g][3] = b;
            }
            __builtin_amdgcn_s_setprio(1);
#pragma unroll
            for (int kb = 0; kb < 4; ++kb) {
                half8 ae = *(const half8*)(eA + (rt * 16 + l15) * HS + kb * 32 + q * 8);
#pragma unroll
                for (int g = 0; g < 4; ++g)
                    acc[g] = __builtin_amdgcn_mfma_f32_16x16x32_f16(ae, wfA[g][kb], acc[g], 0, 0, 0);
            }
            __builtin_amdgcn_s_setprio(0);
#pragma unroll
            for (int r = 0; r < 4; ++r) {
                float h = lstm_one(acc[0][r], acc[1][r], acc[2][r], acc[3][r], cS[rt][r]);
                hOut[(rt * 16 + q * 4 + r) * HS + w * 16 + l15] = (half_t)h;
            }
        }
    }
}

// Decoder LSTM step: input-GEMM replaced by per-lane zx read (d_in fixed across steps).
__device__ __forceinline__ void lstm_step_dec(
    const half_t* __restrict__ zx, const half_t* __restrict__ hA, half_t* __restrict__ hOut,
    const half8 (&wfh)[4][4], float (&cS)[RTMAX][4],
    int w, int q, int l15, int lane, int RT) {
#pragma unroll
    for (int rt = 0; rt < RTMAX; ++rt) {
        if (rt < RT) {
            const half_t* p0 = zx + ((w * RTMAX + rt) * 64 + lane) * 8;
            half8 z0 = *(const half8*)p0;                 // gates i,f
            half8 z1 = *(const half8*)(p0 + ZX_PLANE_H);  // gates g,o
            float4_ acc[4];
#pragma unroll
            for (int r = 0; r < 4; ++r) {
                acc[0][r] = (float)z0[r];
                acc[1][r] = (float)z0[4 + r];
                acc[2][r] = (float)z1[r];
                acc[3][r] = (float)z1[4 + r];
            }
            __builtin_amdgcn_s_setprio(1);
#pragma unroll
            for (int kb = 0; kb < 4; ++kb) {
                half8 ah = *(const half8*)(hA + (rt * 16 + l15) * HS + kb * 32 + q * 8);
#pragma unroll
                for (int g = 0; g < 4; ++g)
                    acc[g] = __builtin_amdgcn_mfma_f32_16x16x32_f16(ah, wfh[g][kb], acc[g], 0, 0, 0);
            }
            __builtin_amdgcn_s_setprio(0);
#pragma unroll
            for (int r = 0; r < 4; ++r) {
                float h = lstm_one(acc[0][r], acc[1][r], acc[2][r], acc[3][r], cS[rt][r]);
                hOut[(rt * 16 + q * 4 + r) * HS + w * 16 + l15] = (half_t)h;
            }
        }
    }
}

// e_t = relu(x_t @ encW^T + enc_b); wave w computes e cols [16w, 16w+16)
__device__ __forceinline__ void enc_proj(
    const half_t* __restrict__ xa, half_t* __restrict__ eOut,
    half8 encWf, float benc, int t, int w, int q, int l15, int RT) {
#pragma unroll
    for (int rt = 0; rt < RTMAX; ++rt) {
        if (rt < RT) {
            half8 af = *(const half8*)(xa + ((t * ROWSMAX) + rt * 16 + l15) * XS + q * 8);
            float4_ a;
            a[0] = benc; a[1] = benc; a[2] = benc; a[3] = benc;
            a = __builtin_amdgcn_mfma_f32_16x16x32_f16(af, encWf, a, 0, 0, 0);
#pragma unroll
            for (int r = 0; r < 4; ++r) {
                float v = a[r];
                v = v > 0.f ? v : 0.f;
                eOut[(rt * 16 + q * 4 + r) * HS + w * 16 + l15] = (half_t)v;
            }
        }
    }
}

// head: o = relu(h @ fc1^T + b1); per-(ct,row) partial dot with fc2 into pred[ct][row].
// wave w: fc1 col-tile (w&3); row-tiles rt = gg, gg+2, gg+4 (gg = w>>2)
__device__ __forceinline__ void head_step(
    const half_t* __restrict__ hc, float (*pred)[ROWSMAX],
    const half8 (&fc1f)[4], float bf1, float wf2,
    int w, int q, int l15, int gg, int RT) {
#pragma unroll
    for (int rp = 0; rp < 3; ++rp) {
        int rt = gg + rp * 2;
        if (rt < RT) {
            float4_ hacc;
            hacc[0] = bf1; hacc[1] = bf1; hacc[2] = bf1; hacc[3] = bf1;
#pragma unroll
            for (int kb = 0; kb < 4; ++kb) {
                half8 af = *(const half8*)(hc + (rt * 16 + l15) * HS + kb * 32 + q * 8);
                hacc = __builtin_amdgcn_mfma_f32_16x16x32_f16(af, fc1f[kb], hacc, 0, 0, 0);
            }
#pragma unroll
            for (int r = 0; r < 4; ++r) {
                float v = hacc[r];
                v = v > 0.f ? v : 0.f;
                v *= wf2;
                v += __shfl_xor(v, 1, 64);
                v += __shfl_xor(v, 2, 64);
                v += __shfl_xor(v, 4, 64);
                v += __shfl_xor(v, 8, 64);
                if (l15 == 0) pred[w & 3][rt * 16 + q * 4 + r] = v;
            }
        }
    }
}

__global__ __launch_bounds__(512, 2) void seq2seq_main_k(
    const float* __restrict__ x,
    const float* __restrict__ enc_b,
    const float* __restrict__ fc1_b,
    const float* __restrict__ fc2_W,
    const float* __restrict__ fc2_b,
    const half_t* __restrict__ wsh,
    const float* __restrict__ be,
    const float* __restrict__ bd,
    float* __restrict__ out) {
    __shared__ __align__(16) char smem[SM_BYTES];
    half_t* xa = (half_t*)smem;
    half_t* eB = (half_t*)(smem + E_OFF);
    half_t* hB = (half_t*)(smem + H_OFF);
    float (*pred)[4][ROWSMAX] = (float(*)[4][ROWSMAX])(smem + PRED_OFF);  // [2][4][80]
    half_t* zx = (half_t*)smem;   // decoder alias over dead xa+e0

    const int tid  = threadIdx.x;
    const int lane = tid & 63;
    const int w    = tid >> 6;        // wave 0..7
    const int q    = lane >> 4;
    const int l15  = lane & 15;
    // SIMD-phase stagger: waves w and w+4 share a SIMD (round-robin mapping);
    // opposite step-phase packs one wave's MFMA burst against the other's
    // activation/LDS burst.
    const int ph   = (w >> 2) & 1;
    const int bid  = blockIdx.x;
    const int big  = (bid < N80);
    const int RT   = big ? 5 : 4;
    const int rows = RT << 4;
    const int n0   = big ? bid * 80 : (N80 * 80 + (bid - N80) * 64);

    const half_t* WihE  = wsh;
    const half_t* WhhE  = wsh + 65536;
    const half_t* WihD  = wsh + 131072;
    const half_t* WhhD  = wsh + 196608;
    const half_t* encWp = wsh + 262144;
    const half_t* fc1p  = wsh + 266240;

    // per-wave biases (prescaled in prep): z col = g*128 + w*16 + l15
    float beR[4], bdR[4];
#pragma unroll
    for (int g = 0; g < 4; ++g) {
        int col = g * 128 + w * 16 + l15;
        beR[g] = be[col];
        bdR[g] = bd[col];
    }
    float benc = enc_b[w * 16 + l15];

    // stage ALL x timesteps into LDS (fp16). 12 t * 80 rows * 4 chunks = 3840 units max.
    for (int it = 0; it < 8; ++it) {
        int unit = tid + it * 512;
        if (unit >= TSTEPS * ROWSMAX * 4) break;
        int t    = unit / (ROWSMAX * 4);
        int rest = unit - t * (ROWSMAX * 4);
        int row  = rest >> 2;
        int c0   = (rest & 3) * 8;
        if (row < rows) {
            const float* p = x + ((size_t)t * NNODES + (n0 + row)) * DIN + c0;
            float4_ a0 = *(const float4_*)p;
            float4_ a1 = *(const float4_*)(p + 4);
            half8 hv;
            hv[0] = (half_t)a0[0]; hv[1] = (half_t)a0[1]; hv[2] = (half_t)a0[2]; hv[3] = (half_t)a0[3];
            hv[4] = (half_t)a1[0]; hv[5] = (half_t)a1[1]; hv[6] = (half_t)a1[2]; hv[7] = (half_t)a1[3];
            *(half8*)(xa + (t * ROWSMAX + row) * XS + c0) = hv;
        }
    }
    // (no h zero-fill needed: t=0 uses lstm_step0, which never reads h)

    float c_reg[RTMAX][4];
#pragma unroll
    for (int rt = 0; rt < RTMAX; ++rt)
#pragma unroll
        for (int r = 0; r < 4; ++r) c_reg[rt][r] = 0.0f;

    // ---- encoder weights into registers (per-wave slice: 128 VGPRs) ----
    half8 wfi[4][4], wfh[4][4];
#pragma unroll
    for (int g = 0; g < 4; ++g)
#pragma unroll
        for (int kb = 0; kb < 4; ++kb) {
            int ct = g * 8 + w;
            wfi[g][kb] = *(const half8*)(WihE + ((size_t)(ct * 4 + kb) * 64 + lane) * 8);
            wfh[g][kb] = *(const half8*)(WhhE + ((size_t)(ct * 4 + kb) * 64 + lane) * 8);
        }
    half8 encWf = *(const half8*)(encWp + (size_t)w * 512 + lane * 8);

    __syncthreads();  // xa ready

    enc_proj(xa, eB, encWf, benc, 0, w, q, l15, RT);
    __syncthreads();  // e0 ready

    // ---- t = 0: h == 0, input-GEMM only ----
    if (!ph) {
        lstm_step0(eB, hB + ESZ, wfi, beR, c_reg, w, q, l15, RT);
        enc_proj(xa, eB + ESZ, encWf, benc, 1, w, q, l15, RT);
    } else {
        enc_proj(xa, eB + ESZ, encWf, benc, 1, w, q, l15, RT);
        lstm_step0(eB, hB + ESZ, wfi, beR, c_reg, w, q, l15, RT);
    }
    __syncthreads();

    int cur = 1;
    // ================= encoder t=1..11: one barrier per step, phase-staggered =========
    for (int t = 1; t < TSTEPS; ++t) {
        const half_t* eCur  = eB + (t & 1) * ESZ;
        half_t*       eNext = eB + ((t & 1) ^ 1) * ESZ;
        const half_t* hCur  = hB + cur * ESZ;
        half_t*       hNext = hB + (cur ^ 1) * ESZ;
        if (!ph) {
            lstm_step(eCur, hCur, hNext, wfi, wfh, beR, c_reg, w, q, l15, RT);
            if (t + 1 < TSTEPS)
                enc_proj(xa, eNext, encWf, benc, t + 1, w, q, l15, RT);
        } else {
            if (t + 1 < TSTEPS)
                enc_proj(xa, eNext, encWf, benc, t + 1, w, q, l15, RT);
            lstm_step(hCur, eCur, hNext, wfh, wfi, beR, c_reg, w, q, l15, RT);
        }
        __syncthreads();
        cur ^= 1;
    }
    // cur == 0; hB[cur] = final encoder h == d_in. xa and e are dead.

    // ---- decoder weights into the same registers; head params ----
#pragma unroll
    for (int g = 0; g < 4; ++g)
#pragma unroll
        for (int kb = 0; kb < 4; ++kb) {
            int ct = g * 8 + w;
            wfi[g][kb] = *(const half8*)(WihD + ((size_t)(ct * 4 + kb) * 64 + lane) * 8);
            wfh[g][kb] = *(const half8*)(WhhD + ((size_t)(ct * 4 + kb) * 64 + lane) * 8);
        }
    half8 fc1f[4];
#pragma unroll
    for (int kb = 0; kb < 4; ++kb)
        fc1f[kb] = *(const half8*)(fc1p + ((size_t)((w & 3) * 4 + kb) * 64 + lane) * 8);
    float bf1 = fc1_b[(w & 3) * 16 + l15];
    float wf2 = fc2_W[(w & 3) * 16 + l15];
    float bf2 = fc2_b[0];
    const int gg = w >> 2;

    // ---- z_x = d_in @ WihD^T + b_d, once (d_in fixed across decoder steps).
    // Per-lane-private packed fp16 layout -> no barrier needed; aliases dead xa/e0.
    {
        const half_t* hfin = hB + cur * ESZ;
#pragma unroll
        for (int rt = 0; rt < RTMAX; ++rt) {
            if (rt < RT) {
                float4_ acc[4];
#pragma unroll
                for (int g = 0; g < 4; ++g) {
                    float b = bdR[g];
                    acc[g][0] = b; acc[g][1] = b; acc[g][2] = b; acc[g][3] = b;
                }
#pragma unroll
                for (int kb = 0; kb < 4; ++kb) {
                    half8 ah = *(const half8*)(hfin + (rt * 16 + l15) * HS + kb * 32 + q * 8);
#pragma unroll
                    for (int g = 0; g < 4; ++g)
                        acc[g] = __builtin_amdgcn_mfma_f32_16x16x32_f16(ah, wfi[g][kb], acc[g], 0, 0, 0);
                }
                half8 z0, z1;
#pragma unroll
                for (int r = 0; r < 4; ++r) {
                    z0[r]     = (half_t)acc[0][r];
                    z0[4 + r] = (half_t)acc[1][r];
                    z1[r]     = (half_t)acc[2][r];
                    z1[4 + r] = (half_t)acc[3][r];
                }
                half_t* p0 = zx + ((w * RTMAX + rt) * 64 + lane) * 8;
                *(half8*)p0 = z0;
                *(half8*)(p0 + ZX_PLANE_H) = z1;
            }
        }
    }

    // ================= decoder: merged segments =================
    // Segment s: { lstm_dec(s) ∥ head(s-1) ∥ out(s-2) } ; barrier.
    // head/lstm only READ h[hc]; pred double-buffer separates head(s-1)/out(s-2).
    int hc = cur;
    for (int s = 0; s < DECS; ++s) {
        lstm_step_dec(zx, hB + hc * ESZ, hB + (hc ^ 1) * ESZ, wfh, c_reg, w, q, l15, lane, RT);
        if (s >= 1)
            head_step(hB + hc * ESZ, pred[(s - 1) & 1], fc1f, bf1, wf2, w, q, l15, gg, RT);
        if (s >= 2 && tid < rows) {
            float sum = pred[s & 1][0][tid] + pred[s & 1][1][tid]
                      + pred[s & 1][2][tid] + pred[s & 1][3][tid] + bf2;
            out[(size_t)(n0 + tid) * DECS + (s - 2)] = sum;
        }
        __syncthreads();
        hc ^= 1;
    }
    // tail: h[hc] = output of lstm(6)
    head_step(hB + hc * ESZ, pred[0], fc1f, bf1, wf2, w, q, l15, gg, RT);  // head(6)
    if (tid < rows) {  // out(5) from pred[1]
        float sum = pred[1][0][tid] + pred[1][1][tid] + pred[1][2][tid] + pred[1][3][tid] + bf2;
        out[(size_t)(n0 + tid) * DECS + 5] = sum;
    }
    __syncthreads();
    if (tid < rows) {  // out(6) from pred[0]
        float sum = pred[0][0][tid] + pred[0][1][tid] + pred[0][2][tid] + pred[0][3][tid] + bf2;
        out[(size_t)(n0 + tid) * DECS + 6] = sum;
    }
}

extern "C" void kernel_launch(void* const* d_in, const int* in_sizes, int n_in,
                              void* d_out, int out_size, void* d_ws, size_t ws_size,
                              hipStream_t stream) {
    (void)in_sizes; (void)n_in; (void)out_size; (void)ws_size;
    const float* x     = (const float*)d_in[0];
    const float* enc_W = (const float*)d_in[1];
    const float* enc_b = (const float*)d_in[2];
    const float* Wih_e = (const float*)d_in[3];
    const float* Whh_e = (const float*)d_in[4];
    const float* bih_e = (const float*)d_in[5];
    const float* bhh_e = (const float*)d_in[6];
    const float* Wih_d = (const float*)d_in[7];
    const float* Whh_d = (const float*)d_in[8];
    const float* bih_d = (const float*)d_in[9];
    const float* bhh_d = (const float*)d_in[10];
    const float* fc1_W = (const float*)d_in[11];
    const float* fc1_b = (const float*)d_in[12];
    const float* fc2_W = (const float*)d_in[13];
    const float* fc2_b = (const float*)d_in[14];

    half_t* wsh = (half_t*)d_ws;
    float*  be  = (float*)((char*)d_ws + WS_FLOAT_OFF);
    float*  bd  = be + 512;

    prep_all_k<<<1074, 256, 0, stream>>>(Wih_e, Whh_e, Wih_d, Whh_d, enc_W, fc1_W,
                                         bih_e, bhh_e, bih_d, bhh_d, wsh, be, bd);

    seq2seq_main_k<<<NB, 512, 0, stream>>>(x, enc_b, fc1_b, fc2_W, fc2_b,
                                           wsh, be, bd, (float*)d_out);
}